// Round 7
// baseline (438.960 us; speedup 1.0000x reference)
//
#include <hip/hip_runtime.h>
#include <hip/hip_fp16.h>

// GCN forward: 3x (GEMM -> normalized scatter-sum -> bias -> relu[except last])
// Gather table and agg<->gemm interfaces are fp16. ep = (src, norm) int2.
// R8: GEMMs on MFMA (v_mfma_f32_16x16x32_f16), swapped operands, W
// pre-swizzled in LDS, X streamed. R9: agg is latency/throughput-bound, NOT
// occupancy-bound; unroll-8 plain loads optimal. R10: hot-address (~30 addr)
// global atomics = disaster, but SPREAD atomics are fine; degree-balance perm
// neutral. R11: trusted baseline 309.8. R12/R13: front fusion, passA LDS-sort,
// B2 LDS staging all ~neutral -> build cost is STRUCTURAL (196-391 blocks
// underfill 256 CUs; 3 passes over edges; 2 sort stages). R14: build v2 =
// k_deg (1.6M spread atomics over 100K deg addrs + coarse hist + fused scan)
// -> k_rs (per-bucket scan: row_start/cursor/dinv) -> k_fill (cursor-atomic
// direct ep scatter). 3 kernels, 782 blocks each, single edge pass each.
// ep intra-list order becomes nondeterministic (fp-tolerance only).

#define ALIGN256(x) (((size_t)(x) + 255) & ~(size_t)255)

#define DEG_EDGES 2048

typedef _Float16 f16;
typedef f16 f16x8 __attribute__((ext_vector_type(8)));
typedef float f32x4 __attribute__((ext_vector_type(4)));

// ---- k_deg: per-node degree (spread global atomics) + coarse histogram +
// ---- fused lastblk scan -> cbase; row_start[N]=E tail.

__global__ __launch_bounds__(256) void k_deg(const int* __restrict__ ei,
                                             int* __restrict__ deg,
                                             int* __restrict__ ccnt,
                                             int* __restrict__ done,
                                             int* __restrict__ cbase,
                                             int* __restrict__ row_start,
                                             int E, int N, int NBUK, int nblk) {
    __shared__ int h[512];
    __shared__ int lastblk;
    int t = threadIdx.x;
    for (int i = t; i < NBUK; i += 256) h[i] = 0;
    __syncthreads();
    int e0 = blockIdx.x * DEG_EDGES;
    int e1 = min(e0 + DEG_EDGES, E);
    for (int e = e0 + t; e < e1; e += 256) {
        int d = ei[E + e];
        atomicAdd(&h[d >> 8], 1);
        atomicAdd(&deg[d], 1);
    }
    __syncthreads();
    for (int i = t; i < NBUK; i += 256) {
        int c = h[i];
        if (c) atomicAdd(&ccnt[i], c);
    }
    __threadfence();
    if (t == 0) lastblk = (atomicAdd(done, 1) == nblk - 1) ? 1 : 0;
    __syncthreads();
    if (!lastblk) return;

    // ---- last block: exclusive scan of ccnt -> cbase ----
    __shared__ int sd[256];
    int i0 = 2 * t, i1 = 2 * t + 1;
    int v0 = (i0 < NBUK) ? ccnt[i0] : 0;
    int v1 = (i1 < NBUK) ? ccnt[i1] : 0;
    int s = v0 + v1;
    sd[t] = s;
    __syncthreads();
    for (int off = 1; off < 256; off <<= 1) {
        int u = (t >= off) ? sd[t - off] : 0;
        __syncthreads();
        sd[t] += u;
        __syncthreads();
    }
    int base = sd[t] - s;
    if (i0 < NBUK) cbase[i0] = base;
    if (i1 < NBUK) cbase[i1] = base + v0;
    if (t == 0) { cbase[NBUK] = E; row_start[N] = E; }
}

// ---- k_rs: per-bucket (256 nodes) scan of deg -> row_start, cursor, dinv ---

__global__ __launch_bounds__(256) void k_rs(const int* __restrict__ deg,
                                            const int* __restrict__ cbase,
                                            int* __restrict__ row_start,
                                            int* __restrict__ cursor,
                                            float* __restrict__ dinv, int N) {
    __shared__ int sd[256];
    int b = blockIdx.x;
    int t = threadIdx.x;
    int node = (b << 8) + t;
    int c = (node < N) ? deg[node] : 0;
    sd[t] = c;
    __syncthreads();
    for (int off = 1; off < 256; off <<= 1) {
        int u = (t >= off) ? sd[t - off] : 0;
        __syncthreads();
        sd[t] += u;
        __syncthreads();
    }
    int excl = sd[t] - c;
    if (node < N) {
        int rs = cbase[b] + excl;
        row_start[node] = rs;
        cursor[node] = rs;
        dinv[node] = 1.0f / sqrtf((float)(c + 1));   // +1 self-loop
    }
}

// ---- k_fill: direct ep scatter via per-node cursor atomics (16 avg/addr) ---

__global__ __launch_bounds__(256) void k_fill(const int* __restrict__ ei,
                                              const float* __restrict__ dinv,
                                              int* __restrict__ cursor,
                                              int2* __restrict__ ep, int E) {
    int e0 = blockIdx.x * DEG_EDGES;
    int e1 = min(e0 + DEG_EDGES, E);
    for (int e = e0 + threadIdx.x; e < e1; e += 256) {
        int src = ei[e];
        int dst = ei[E + e];
        float nrm = dinv[src] * dinv[dst];
        int pos = atomicAdd(&cursor[dst], 1);
        ep[pos] = make_int2(src, __float_as_int(nrm));
    }
}

// ---------------- MFMA GEMM: Y[N,OUT](fp16) = X[N,K] @ W[K,OUT] -------------
// Block = 256 thr = 4 waves; 64 rows/block (16/wave), OUT cols via NF
// fragments. v_mfma_f32_16x16x32_f16, fp32 accum. SWAPPED operands: W in A
// slot, X rows in B slot -> D maps row=lane&15, cols=4*(lane>>4)+reg -> 8B
// contiguous stores. k = 8h+j bijection shared by both operands. W staged to
// LDS once, pre-swizzled, conflict-free ds_read_b128; no barrier in K loop.

template <int K, int OUT, int NF, typename XT>
__global__ __launch_bounds__(256) void k_mgemm(const XT* __restrict__ X,
                                               const float* __restrict__ W,
                                               __half* __restrict__ Y, int N) {
    constexpr int NC = NF * 16;     // padded col count
    constexpr int NT = K / 32;      // k-steps
    __shared__ f16 Wl[NT * NF * 4 * 128];   // [t][f][h][nn][j], 16B/fragment

    int tid = threadIdx.x;
    for (int idx = tid; idx < K * NC; idx += 256) {
        int k = idx / NC;
        int n = idx - k * NC;
        float v = (n < OUT) ? W[k * OUT + n] : 0.0f;
        int t = k >> 5, h = (k >> 3) & 3, j = k & 7, f = n >> 4, nn = n & 15;
        Wl[((t * NF + f) * 4 + h) * 128 + nn * 8 + j] = (f16)v;
    }
    __syncthreads();

    int lane = tid & 63;
    int wid = tid >> 6;
    int h = lane >> 4;          // k-subblock selector (k = 8h+j)
    int nn = lane & 15;         // output row within wave tile
    int row = blockIdx.x * 64 + (wid << 4) + nn;
    bool valid = row < N;

    f32x4 acc[NF];
#pragma unroll
    for (int f = 0; f < NF; ++f) acc[f] = (f32x4){0.f, 0.f, 0.f, 0.f};

#pragma unroll
    for (int t = 0; t < NT; ++t) {
        f16x8 xf;
        if (valid) {
            if constexpr (sizeof(XT) == 4) {
                const float* xp = (const float*)X + (size_t)row * K + (t << 5) + (h << 3);
                float4 u0 = *(const float4*)xp;
                float4 u1 = *(const float4*)(xp + 4);
                xf[0] = (f16)u0.x; xf[1] = (f16)u0.y; xf[2] = (f16)u0.z; xf[3] = (f16)u0.w;
                xf[4] = (f16)u1.x; xf[5] = (f16)u1.y; xf[6] = (f16)u1.z; xf[7] = (f16)u1.w;
            } else {
                xf = *(const f16x8*)((const __half*)X + (size_t)row * K + (t << 5) + (h << 3));
            }
        } else {
#pragma unroll
            for (int j = 0; j < 8; ++j) xf[j] = (f16)0.f;
        }
#pragma unroll
        for (int f = 0; f < NF; ++f) {
            f16x8 wf = *(const f16x8*)&Wl[((t * NF + f) * 4 + h) * 128 + nn * 8];
            acc[f] = __builtin_amdgcn_mfma_f32_16x16x32_f16(wf, xf, acc[f], 0, 0, 0);
        }
    }

    if (valid) {
#pragma unroll
        for (int f = 0; f < NF; ++f) {
            int c = (f << 4) + (h << 2);    // 4 consecutive cols c..c+3
            if (c < OUT) {
                __half2 p0 = __floats2half2_rn(acc[f][0], acc[f][1]);
                __half2 p1 = __floats2half2_rn(acc[f][2], acc[f][3]);
                uint2 pk = make_uint2(*(unsigned int*)&p0, *(unsigned int*)&p1);
                *(uint2*)&Y[(size_t)row * OUT + c] = pk;
            }
        }
    }
}

// ---------------- Aggregation (fp16 gather, fp32 accumulate) ----------------
// 8 lanes/node (lane = 8 fp16 feats = 16B), 8 nodes/wave, unroll x8:
// up to 64 independent 16B gathers in flight per wave. ep = (src,norm) int2.

__device__ __forceinline__ void fma8(float4& a0, float4& a1, uint4 hv, float w) {
    __half2* hp = (__half2*)&hv;
    float2 f0 = __half22float2(hp[0]);
    float2 f1 = __half22float2(hp[1]);
    float2 f2 = __half22float2(hp[2]);
    float2 f3 = __half22float2(hp[3]);
    a0.x += f0.x * w; a0.y += f0.y * w; a0.z += f1.x * w; a0.w += f1.y * w;
    a1.x += f2.x * w; a1.y += f2.y * w; a1.z += f3.x * w; a1.w += f3.y * w;
}

template <int NV, int F, int RELU, typename OutT>
__global__ __launch_bounds__(256) void k_agg(const __half* __restrict__ H,
                                             const int* __restrict__ row_start,
                                             const int2* __restrict__ ep,
                                             const float* __restrict__ dinv,
                                             const float* __restrict__ bias,
                                             OutT* __restrict__ out, int N) {
    int tid = threadIdx.x;
    int lane = tid & 63;
    int sub = lane >> 3;        // node within wave (0..7)
    int lq = lane & 7;          // 8-feature chunk
    int node = blockIdx.x * 32 + (tid >> 6) * 8 + sub;
    if (node >= N) return;
    const bool act = (NV == 8) || (lq < NV);

    int jb = row_start[node];
    int je = row_start[node + 1];
    float dv = dinv[node];

    float4 a0 = make_float4(0.f, 0.f, 0.f, 0.f);
    float4 a1 = make_float4(0.f, 0.f, 0.f, 0.f);
    if (act) {
        uint4 hv = *(const uint4*)&H[(size_t)node * F + 8 * lq];
        fma8(a0, a1, hv, dv * dv);
    }

    int j = jb;
    for (; j + 8 <= je; j += 8) {
        int2 e0 = ep[j],     e1 = ep[j + 1], e2 = ep[j + 2], e3 = ep[j + 3];
        int2 e4 = ep[j + 4], e5 = ep[j + 5], e6 = ep[j + 6], e7 = ep[j + 7];
        if (act) {
            uint4 h0 = *(const uint4*)&H[(size_t)e0.x * F + 8 * lq];
            uint4 h1 = *(const uint4*)&H[(size_t)e1.x * F + 8 * lq];
            uint4 h2 = *(const uint4*)&H[(size_t)e2.x * F + 8 * lq];
            uint4 h3 = *(const uint4*)&H[(size_t)e3.x * F + 8 * lq];
            uint4 h4 = *(const uint4*)&H[(size_t)e4.x * F + 8 * lq];
            uint4 h5 = *(const uint4*)&H[(size_t)e5.x * F + 8 * lq];
            uint4 h6 = *(const uint4*)&H[(size_t)e6.x * F + 8 * lq];
            uint4 h7 = *(const uint4*)&H[(size_t)e7.x * F + 8 * lq];
            fma8(a0, a1, h0, __int_as_float(e0.y));
            fma8(a0, a1, h1, __int_as_float(e1.y));
            fma8(a0, a1, h2, __int_as_float(e2.y));
            fma8(a0, a1, h3, __int_as_float(e3.y));
            fma8(a0, a1, h4, __int_as_float(e4.y));
            fma8(a0, a1, h5, __int_as_float(e5.y));
            fma8(a0, a1, h6, __int_as_float(e6.y));
            fma8(a0, a1, h7, __int_as_float(e7.y));
        }
    }
    for (; j + 2 <= je; j += 2) {
        int2 e0 = ep[j], e1 = ep[j + 1];
        if (act) {
            uint4 h0 = *(const uint4*)&H[(size_t)e0.x * F + 8 * lq];
            uint4 h1 = *(const uint4*)&H[(size_t)e1.x * F + 8 * lq];
            fma8(a0, a1, h0, __int_as_float(e0.y));
            fma8(a0, a1, h1, __int_as_float(e1.y));
        }
    }
    if (j < je) {
        int2 e = ep[j];
        if (act) {
            uint4 h = *(const uint4*)&H[(size_t)e.x * F + 8 * lq];
            fma8(a0, a1, h, __int_as_float(e.y));
        }
    }

    if (act) {
        float4 b0 = *(const float4*)&bias[8 * lq];
        float4 b1 = *(const float4*)&bias[8 * lq + 4];
        a0.x += b0.x; a0.y += b0.y; a0.z += b0.z; a0.w += b0.w;
        a1.x += b1.x; a1.y += b1.y; a1.z += b1.z; a1.w += b1.w;
        if (RELU) {
            a0.x = fmaxf(a0.x, 0.f); a0.y = fmaxf(a0.y, 0.f);
            a0.z = fmaxf(a0.z, 0.f); a0.w = fmaxf(a0.w, 0.f);
            a1.x = fmaxf(a1.x, 0.f); a1.y = fmaxf(a1.y, 0.f);
            a1.z = fmaxf(a1.z, 0.f); a1.w = fmaxf(a1.w, 0.f);
        }
        if constexpr (sizeof(OutT) == 2) {
            __half2 p0 = __floats2half2_rn(a0.x, a0.y);
            __half2 p1 = __floats2half2_rn(a0.z, a0.w);
            __half2 p2 = __floats2half2_rn(a1.x, a1.y);
            __half2 p3 = __floats2half2_rn(a1.z, a1.w);
            uint4 pk = make_uint4(*(unsigned int*)&p0, *(unsigned int*)&p1,
                                  *(unsigned int*)&p2, *(unsigned int*)&p3);
            *(uint4*)&out[(size_t)node * F + 8 * lq] = pk;
        } else {
            *(float4*)&out[(size_t)node * F + 8 * lq] = a0;
            *(float4*)&out[(size_t)node * F + 8 * lq + 4] = a1;
        }
    }
}

// ---------------- launch ----------------

extern "C" void kernel_launch(void* const* d_in, const int* in_sizes, int n_in,
                              void* d_out, int out_size, void* d_ws, size_t ws_size,
                              hipStream_t stream) {
    const float* x  = (const float*)d_in[0];
    const int*   ei = (const int*)d_in[1];
    const float* W0 = (const float*)d_in[2];
    const float* b0 = (const float*)d_in[3];
    const float* W1 = (const float*)d_in[4];
    const float* b1 = (const float*)d_in[5];
    const float* W2 = (const float*)d_in[6];
    const float* b2 = (const float*)d_in[7];
    float* out = (float*)d_out;

    const int N = in_sizes[0] / 128;
    const int E = in_sizes[1] / 2;
    const int NBUK = (N + 255) >> 8;   // coarse buckets of 256 nodes (<=512)

    char* w = (char*)d_ws;
    size_t off = 0;
    // zeroed stretch: ccnt[NBUK], done, deg[N]
    int*    ccnt      = (int*)(w + off);    off = ALIGN256(off + (size_t)(NBUK + 1 + N) * 4);
    int*    done      = ccnt + NBUK;
    int*    deg       = ccnt + NBUK + 1;
    int*    cbase     = (int*)(w + off);    off = ALIGN256(off + (size_t)(NBUK + 1) * 4);
    int*    row_start = (int*)(w + off);    off = ALIGN256(off + (size_t)(N + 1) * 4);
    int*    cursor    = (int*)(w + off);    off = ALIGN256(off + (size_t)N * 4);
    float*  dinv      = (float*)(w + off);  off = ALIGN256(off + (size_t)N * 4);
    int2*   ep        = (int2*)(w + off);   off = ALIGN256(off + (size_t)E * 8);
    __half* bufH      = (__half*)(w + off); off = ALIGN256(off + (size_t)N * 64 * 2);
    __half* bufG      = (__half*)(w + off); off = ALIGN256(off + (size_t)N * 64 * 2);

    const int gGemm = (N + 63) / 64;
    const int gAgg  = (N + 31) / 32;
    const int gE    = (E + DEG_EDGES - 1) / DEG_EDGES;

    hipMemsetAsync(ccnt, 0, (size_t)(NBUK + 1 + N) * 4, stream);
    k_mgemm<128, 64, 4><<<gGemm, 256, 0, stream>>>(x, W0, bufH, N);
    k_deg<<<gE, 256, 0, stream>>>(ei, deg, ccnt, done, cbase, row_start, E, N, NBUK, gE);
    k_rs<<<NBUK, 256, 0, stream>>>(deg, cbase, row_start, cursor, dinv, N);
    k_fill<<<gE, 256, 0, stream>>>(ei, dinv, cursor, ep, E);

    k_agg<8, 64, 1, __half><<<gAgg, 256, 0, stream>>>(bufH, row_start, ep, dinv, b0, bufG, N);
    k_mgemm<64, 64, 4><<<gGemm, 256, 0, stream>>>(bufG, W1, bufH, N);
    k_agg<8, 64, 1, __half><<<gAgg, 256, 0, stream>>>(bufH, row_start, ep, dinv, b1, bufG, N);
    k_mgemm<64, 40, 3><<<gGemm, 256, 0, stream>>>(bufG, W2, bufH, N);
    k_agg<5, 40, 0, float><<<gAgg, 256, 0, stream>>>(bufH, row_start, ep, dinv, b2, out, N);
}

// Round 8
// 312.697 us; speedup vs baseline: 1.4038x; 1.4038x over previous
//
#include <hip/hip_runtime.h>
#include <hip/hip_fp16.h>

// GCN forward: 3x (GEMM -> normalized scatter-sum -> bias -> relu[except last])
// Gather table and agg<->gemm interfaces are fp16. ep = (src, norm) int2 —
// precomputed norm. CSR built with ZERO global atomics (R14 lesson: 1.6M
// random-address global atomics = ~70ns each, 51MB write-amp -> +130us;
// LDS-bucket aggregation is the only fast path. R10: hot-address atomics
// even worse). R8: GEMMs on MFMA (v_mfma_f32_16x16x32_f16), swapped operands,
// W pre-swizzled in LDS. R9: agg latency/throughput-bound, unroll-8 plain
// loads optimal. R12/R13/R14: front fusion, passA LDS-sort, atomic build all
// neutral-to-bad -> R11 build structure validated by elimination. R15: mgemm
// X-loads hoisted out of the K-loop (R12 evidence: VGPR=28 = register-starved
// 2-loads-in-flight schedule; hoisting gives 8 independent loads -> MLP 8x).

#define ALIGN256(x) (((size_t)(x) + 255) & ~(size_t)255)

typedef _Float16 f16;
typedef f16 f16x8 __attribute__((ext_vector_type(8)));
typedef float f32x4 __attribute__((ext_vector_type(4)));

// ---------------- coarse histogram + fused scan (last block) ----------------

__global__ __launch_bounds__(256) void k_coarse(const int* __restrict__ ei,
                                                int* __restrict__ ccnt,
                                                int* __restrict__ done,
                                                int* __restrict__ cbase,
                                                int* __restrict__ cpos,
                                                int* __restrict__ row_start,
                                                int E, int N, int NBUK, int nblk) {
    __shared__ int h[512];
    __shared__ int lastblk;
    int t = threadIdx.x;
    for (int i = t; i < NBUK; i += 256) h[i] = 0;
    __syncthreads();
    int e0 = blockIdx.x * 8192;
    int e1 = min(e0 + 8192, E);
    for (int e = e0 + t; e < e1; e += 256) atomicAdd(&h[ei[E + e] >> 8], 1);
    __syncthreads();
    for (int i = t; i < NBUK; i += 256) {
        int c = h[i];
        if (c) atomicAdd(&ccnt[i], c);
    }
    __threadfence();
    if (t == 0) lastblk = (atomicAdd(done, 1) == nblk - 1) ? 1 : 0;
    __syncthreads();
    if (!lastblk) return;

    __shared__ int sd[256];
    int i0 = 2 * t, i1 = 2 * t + 1;
    int v0 = (i0 < NBUK) ? ccnt[i0] : 0;
    int v1 = (i1 < NBUK) ? ccnt[i1] : 0;
    int s = v0 + v1;
    sd[t] = s;
    __syncthreads();
    for (int off = 1; off < 256; off <<= 1) {
        int u = (t >= off) ? sd[t - off] : 0;
        __syncthreads();
        sd[t] += u;
        __syncthreads();
    }
    int base = sd[t] - s;
    if (i0 < NBUK) { cbase[i0] = base;      cpos[i0] = base; }
    if (i1 < NBUK) { cbase[i1] = base + v0; cpos[i1] = base + v0; }
    if (t == 0) { cbase[NBUK] = E; row_start[N] = E; }
}

// ---------------- pass A: coarse scatter; stage entry = (dst&255)<<24 | src -

__global__ __launch_bounds__(256) void k_passA(const int* __restrict__ ei,
                                               int* __restrict__ cpos,
                                               unsigned int* __restrict__ stage,
                                               int E, int NBUK) {
    __shared__ int h[512];
    __shared__ int base[512];
    int t = threadIdx.x;
    for (int i = t; i < NBUK; i += 256) h[i] = 0;
    __syncthreads();
    int e0 = blockIdx.x * 8192;
    int e1 = min(e0 + 8192, E);
    for (int e = e0 + t; e < e1; e += 256) atomicAdd(&h[ei[E + e] >> 8], 1);
    __syncthreads();
    for (int b = t; b < NBUK; b += 256) {
        int c = h[b];
        base[b] = c ? atomicAdd(&cpos[b], c) : 0;
        h[b] = 0;
    }
    __syncthreads();
    for (int e = e0 + t; e < e1; e += 256) {
        unsigned int s = (unsigned int)ei[e];
        int d = ei[E + e];
        int b = d >> 8;
        int off = base[b] + atomicAdd(&h[b], 1);
        stage[off] = ((unsigned int)(d & 255) << 24) | s;
    }
}

// ---------------- B1: per-bucket node counts (LDS atomics) -> row_start, dinv

__global__ __launch_bounds__(256) void k_B1(const unsigned int* __restrict__ stage,
                                            const int* __restrict__ cbase,
                                            int* __restrict__ row_start,
                                            float* __restrict__ dinv, int N) {
    __shared__ int cnt[256];
    __shared__ int sd[256];
    int b = blockIdx.x;
    int n0 = b << 8;
    int t = threadIdx.x;
    cnt[t] = 0;
    __syncthreads();
    int s0 = cbase[b], s1 = cbase[b + 1];
    for (int j = s0 + t; j < s1; j += 256) atomicAdd(&cnt[stage[j] >> 24], 1);
    __syncthreads();
    int c = cnt[t];
    sd[t] = c;
    __syncthreads();
    for (int off = 1; off < 256; off <<= 1) {
        int u = (t >= off) ? sd[t - off] : 0;
        __syncthreads();
        sd[t] += u;
        __syncthreads();
    }
    int excl = sd[t] - c;
    int node = n0 + t;
    if (node < N) {
        row_start[node] = s0 + excl;
        dinv[node] = 1.0f / sqrtf((float)(c + 1));   // +1 self-loop
    }
}

// ---------------- B2: fine scatter within bucket -> ep = (src, norm) --------

__global__ __launch_bounds__(256) void k_B2(const unsigned int* __restrict__ stage,
                                            const int* __restrict__ cbase,
                                            const int* __restrict__ row_start,
                                            const float* __restrict__ dinv,
                                            int2* __restrict__ ep, int N) {
    __shared__ int lpos[256];
    __shared__ float ld[256];
    int b = blockIdx.x;
    int n0 = b << 8;
    int t = threadIdx.x;
    int node = n0 + t;
    if (node < N) {
        lpos[t] = row_start[node];
        ld[t] = dinv[node];
    }
    __syncthreads();
    int s0 = cbase[b], s1 = cbase[b + 1];
    for (int j = s0 + t; j < s1; j += 256) {
        unsigned int v = stage[j];
        int li = v >> 24;
        int src = v & 0xFFFFFF;
        int slot = atomicAdd(&lpos[li], 1);
        ep[slot] = make_int2(src, __float_as_int(dinv[src] * ld[li]));
    }
}

// ---------------- MFMA GEMM: Y[N,OUT](fp16) = X[N,K] @ W[K,OUT] -------------
// Block = 256 thr = 4 waves; 64 rows/block (16/wave), OUT cols via NF
// fragments. v_mfma_f32_16x16x32_f16, fp32 accum. SWAPPED operands: W in A
// slot, X rows in B slot -> D maps row=lane&15, cols=4*(lane>>4)+reg -> 8B
// contiguous stores. k = 8h+j bijection shared by both operands. W staged to
// LDS once, pre-swizzled, conflict-free ds_read_b128; no barrier in K loop.
// R15: ALL X loads hoisted before the MFMA loop (8 independent global loads
// in flight vs compiler's register-starved 2 at VGPR=28 — R12 counters).

template <int K, int OUT, int NF, typename XT>
__global__ __launch_bounds__(256) void k_mgemm(const XT* __restrict__ X,
                                               const float* __restrict__ W,
                                               __half* __restrict__ Y, int N) {
    constexpr int NC = NF * 16;     // padded col count
    constexpr int NT = K / 32;      // k-steps
    __shared__ f16 Wl[NT * NF * 4 * 128];   // [t][f][h][nn][j], 16B/fragment

    int tid = threadIdx.x;
    for (int idx = tid; idx < K * NC; idx += 256) {
        int k = idx / NC;
        int n = idx - k * NC;
        float v = (n < OUT) ? W[k * OUT + n] : 0.0f;
        int t = k >> 5, h = (k >> 3) & 3, j = k & 7, f = n >> 4, nn = n & 15;
        Wl[((t * NF + f) * 4 + h) * 128 + nn * 8 + j] = (f16)v;
    }
    __syncthreads();

    int lane = tid & 63;
    int wid = tid >> 6;
    int h = lane >> 4;          // k-subblock selector (k = 8h+j)
    int nn = lane & 15;         // output row within wave tile
    int row = blockIdx.x * 64 + (wid << 4) + nn;
    bool valid = row < N;

    // ---- hoisted X loads: all NT fragments issued back-to-back ----
    f16x8 xf[NT];
    if (valid) {
        if constexpr (sizeof(XT) == 4) {
            float4 u[NT][2];
            const float* xb = (const float*)X + (size_t)row * K + (h << 3);
#pragma unroll
            for (int t = 0; t < NT; ++t) {
                u[t][0] = *(const float4*)(xb + (t << 5));
                u[t][1] = *(const float4*)(xb + (t << 5) + 4);
            }
#pragma unroll
            for (int t = 0; t < NT; ++t) {
                xf[t][0] = (f16)u[t][0].x; xf[t][1] = (f16)u[t][0].y;
                xf[t][2] = (f16)u[t][0].z; xf[t][3] = (f16)u[t][0].w;
                xf[t][4] = (f16)u[t][1].x; xf[t][5] = (f16)u[t][1].y;
                xf[t][6] = (f16)u[t][1].z; xf[t][7] = (f16)u[t][1].w;
            }
        } else {
            const __half* xb = (const __half*)X + (size_t)row * K + (h << 3);
#pragma unroll
            for (int t = 0; t < NT; ++t)
                xf[t] = *(const f16x8*)(xb + (t << 5));
        }
    } else {
#pragma unroll
        for (int t = 0; t < NT; ++t)
#pragma unroll
            for (int j = 0; j < 8; ++j) xf[t][j] = (f16)0.f;
    }

    f32x4 acc[NF];
#pragma unroll
    for (int f = 0; f < NF; ++f) acc[f] = (f32x4){0.f, 0.f, 0.f, 0.f};

#pragma unroll
    for (int t = 0; t < NT; ++t) {
#pragma unroll
        for (int f = 0; f < NF; ++f) {
            f16x8 wf = *(const f16x8*)&Wl[((t * NF + f) * 4 + h) * 128 + nn * 8];
            acc[f] = __builtin_amdgcn_mfma_f32_16x16x32_f16(wf, xf[t], acc[f], 0, 0, 0);
        }
    }

    if (valid) {
#pragma unroll
        for (int f = 0; f < NF; ++f) {
            int c = (f << 4) + (h << 2);    // 4 consecutive cols c..c+3
            if (c < OUT) {
                __half2 p0 = __floats2half2_rn(acc[f][0], acc[f][1]);
                __half2 p1 = __floats2half2_rn(acc[f][2], acc[f][3]);
                uint2 pk = make_uint2(*(unsigned int*)&p0, *(unsigned int*)&p1);
                *(uint2*)&Y[(size_t)row * OUT + c] = pk;
            }
        }
    }
}

// ---------------- Aggregation (fp16 gather, fp32 accumulate) ----------------
// 8 lanes/node (lane = 8 fp16 feats = 16B), 8 nodes/wave, unroll x8:
// up to 64 independent 16B gathers in flight per wave. ep = (src,norm) int2.

__device__ __forceinline__ void fma8(float4& a0, float4& a1, uint4 hv, float w) {
    __half2* hp = (__half2*)&hv;
    float2 f0 = __half22float2(hp[0]);
    float2 f1 = __half22float2(hp[1]);
    float2 f2 = __half22float2(hp[2]);
    float2 f3 = __half22float2(hp[3]);
    a0.x += f0.x * w; a0.y += f0.y * w; a0.z += f1.x * w; a0.w += f1.y * w;
    a1.x += f2.x * w; a1.y += f2.y * w; a1.z += f3.x * w; a1.w += f3.y * w;
}

template <int NV, int F, int RELU, typename OutT>
__global__ __launch_bounds__(256) void k_agg(const __half* __restrict__ H,
                                             const int* __restrict__ row_start,
                                             const int2* __restrict__ ep,
                                             const float* __restrict__ dinv,
                                             const float* __restrict__ bias,
                                             OutT* __restrict__ out, int N) {
    int tid = threadIdx.x;
    int lane = tid & 63;
    int sub = lane >> 3;        // node within wave (0..7)
    int lq = lane & 7;          // 8-feature chunk
    int node = blockIdx.x * 32 + (tid >> 6) * 8 + sub;
    if (node >= N) return;
    const bool act = (NV == 8) || (lq < NV);

    int jb = row_start[node];
    int je = row_start[node + 1];
    float dv = dinv[node];

    float4 a0 = make_float4(0.f, 0.f, 0.f, 0.f);
    float4 a1 = make_float4(0.f, 0.f, 0.f, 0.f);
    if (act) {
        uint4 hv = *(const uint4*)&H[(size_t)node * F + 8 * lq];
        fma8(a0, a1, hv, dv * dv);
    }

    int j = jb;
    for (; j + 8 <= je; j += 8) {
        int2 e0 = ep[j],     e1 = ep[j + 1], e2 = ep[j + 2], e3 = ep[j + 3];
        int2 e4 = ep[j + 4], e5 = ep[j + 5], e6 = ep[j + 6], e7 = ep[j + 7];
        if (act) {
            uint4 h0 = *(const uint4*)&H[(size_t)e0.x * F + 8 * lq];
            uint4 h1 = *(const uint4*)&H[(size_t)e1.x * F + 8 * lq];
            uint4 h2 = *(const uint4*)&H[(size_t)e2.x * F + 8 * lq];
            uint4 h3 = *(const uint4*)&H[(size_t)e3.x * F + 8 * lq];
            uint4 h4 = *(const uint4*)&H[(size_t)e4.x * F + 8 * lq];
            uint4 h5 = *(const uint4*)&H[(size_t)e5.x * F + 8 * lq];
            uint4 h6 = *(const uint4*)&H[(size_t)e6.x * F + 8 * lq];
            uint4 h7 = *(const uint4*)&H[(size_t)e7.x * F + 8 * lq];
            fma8(a0, a1, h0, __int_as_float(e0.y));
            fma8(a0, a1, h1, __int_as_float(e1.y));
            fma8(a0, a1, h2, __int_as_float(e2.y));
            fma8(a0, a1, h3, __int_as_float(e3.y));
            fma8(a0, a1, h4, __int_as_float(e4.y));
            fma8(a0, a1, h5, __int_as_float(e5.y));
            fma8(a0, a1, h6, __int_as_float(e6.y));
            fma8(a0, a1, h7, __int_as_float(e7.y));
        }
    }
    for (; j + 2 <= je; j += 2) {
        int2 e0 = ep[j], e1 = ep[j + 1];
        if (act) {
            uint4 h0 = *(const uint4*)&H[(size_t)e0.x * F + 8 * lq];
            uint4 h1 = *(const uint4*)&H[(size_t)e1.x * F + 8 * lq];
            fma8(a0, a1, h0, __int_as_float(e0.y));
            fma8(a0, a1, h1, __int_as_float(e1.y));
        }
    }
    if (j < je) {
        int2 e = ep[j];
        if (act) {
            uint4 h = *(const uint4*)&H[(size_t)e.x * F + 8 * lq];
            fma8(a0, a1, h, __int_as_float(e.y));
        }
    }

    if (act) {
        float4 b0 = *(const float4*)&bias[8 * lq];
        float4 b1 = *(const float4*)&bias[8 * lq + 4];
        a0.x += b0.x; a0.y += b0.y; a0.z += b0.z; a0.w += b0.w;
        a1.x += b1.x; a1.y += b1.y; a1.z += b1.z; a1.w += b1.w;
        if (RELU) {
            a0.x = fmaxf(a0.x, 0.f); a0.y = fmaxf(a0.y, 0.f);
            a0.z = fmaxf(a0.z, 0.f); a0.w = fmaxf(a0.w, 0.f);
            a1.x = fmaxf(a1.x, 0.f); a1.y = fmaxf(a1.y, 0.f);
            a1.z = fmaxf(a1.z, 0.f); a1.w = fmaxf(a1.w, 0.f);
        }
        if constexpr (sizeof(OutT) == 2) {
            __half2 p0 = __floats2half2_rn(a0.x, a0.y);
            __half2 p1 = __floats2half2_rn(a0.z, a0.w);
            __half2 p2 = __floats2half2_rn(a1.x, a1.y);
            __half2 p3 = __floats2half2_rn(a1.z, a1.w);
            uint4 pk = make_uint4(*(unsigned int*)&p0, *(unsigned int*)&p1,
                                  *(unsigned int*)&p2, *(unsigned int*)&p3);
            *(uint4*)&out[(size_t)node * F + 8 * lq] = pk;
        } else {
            *(float4*)&out[(size_t)node * F + 8 * lq] = a0;
            *(float4*)&out[(size_t)node * F + 8 * lq + 4] = a1;
        }
    }
}

// ---------------- launch ----------------

extern "C" void kernel_launch(void* const* d_in, const int* in_sizes, int n_in,
                              void* d_out, int out_size, void* d_ws, size_t ws_size,
                              hipStream_t stream) {
    const float* x  = (const float*)d_in[0];
    const int*   ei = (const int*)d_in[1];
    const float* W0 = (const float*)d_in[2];
    const float* b0 = (const float*)d_in[3];
    const float* W1 = (const float*)d_in[4];
    const float* b1 = (const float*)d_in[5];
    const float* W2 = (const float*)d_in[6];
    const float* b2 = (const float*)d_in[7];
    float* out = (float*)d_out;

    const int N = in_sizes[0] / 128;
    const int E = in_sizes[1] / 2;
    const int NBUK = (N + 255) >> 8;   // coarse buckets of 256 nodes (<=512)

    char* w = (char*)d_ws;
    size_t off = 0;
    // zeroed stretch: ccnt[NBUK], done
    int*    ccnt      = (int*)(w + off);    off = ALIGN256(off + (size_t)(NBUK + 1) * 4);
    int*    done      = ccnt + NBUK;
    int*    cbase     = (int*)(w + off);    off = ALIGN256(off + (size_t)(NBUK + 1) * 4);
    int*    cpos      = (int*)(w + off);    off = ALIGN256(off + (size_t)NBUK * 4);
    int*    row_start = (int*)(w + off);    off = ALIGN256(off + (size_t)(N + 1) * 4);
    float*  dinv      = (float*)(w + off);  off = ALIGN256(off + (size_t)N * 4);
    int2*   ep        = (int2*)(w + off);   off = ALIGN256(off + (size_t)E * 8);
    __half* bufH      = (__half*)(w + off); off = ALIGN256(off + (size_t)N * 64 * 2);
    __half* bufG      = (__half*)(w + off); off = ALIGN256(off + (size_t)N * 64 * 2);
    unsigned int* stage = (unsigned int*)bufG;   // dead before agg1 writes bufG

    const int gGemm = (N + 63) / 64;
    const int gAgg  = (N + 31) / 32;
    const int gPA   = (E + 8191) / 8192;

    hipMemsetAsync(ccnt, 0, (size_t)(NBUK + 1) * 4, stream);
    k_mgemm<128, 64, 4><<<gGemm, 256, 0, stream>>>(x, W0, bufH, N);
    k_coarse<<<gPA, 256, 0, stream>>>(ei, ccnt, done, cbase, cpos, row_start, E, N, NBUK, gPA);
    k_passA<<<gPA, 256, 0, stream>>>(ei, cpos, stage, E, NBUK);
    k_B1<<<NBUK, 256, 0, stream>>>(stage, cbase, row_start, dinv, N);
    k_B2<<<NBUK, 256, 0, stream>>>(stage, cbase, row_start, dinv, ep, N);

    k_agg<8, 64, 1, __half><<<gAgg, 256, 0, stream>>>(bufH, row_start, ep, dinv, b0, bufG, N);
    k_mgemm<64, 64, 4><<<gGemm, 256, 0, stream>>>(bufG, W1, bufH, N);
    k_agg<8, 64, 1, __half><<<gAgg, 256, 0, stream>>>(bufH, row_start, ep, dinv, b1, bufG, N);
    k_mgemm<64, 40, 3><<<gGemm, 256, 0, stream>>>(bufG, W2, bufH, N);
    k_agg<5, 40, 0, float><<<gAgg, 256, 0, stream>>>(bufH, row_start, ep, dinv, b2, out, N);
}

// Round 9
// 309.055 us; speedup vs baseline: 1.4203x; 1.0118x over previous
//
#include <hip/hip_runtime.h>
#include <hip/hip_fp16.h>

// GCN forward: 3x (GEMM -> normalized scatter-sum -> bias -> relu[except last])
// Gather table and agg<->gemm interfaces are fp16. ep = (src, norm) int2 —
// precomputed norm. CSR built with ZERO global atomics (R14: 1.6M random-addr
// global atomics = ~70ns each -> +130us; R10: hot-address even worse; LDS
// aggregation is the only fast path). R8: GEMMs on MFMA, swapped operands, W
// pre-swizzled in LDS. R9: agg latency/throughput-bound, unroll-8 optimal.
// R12/R13/R14/R15: front fusion, passA LDS-sort, atomic build, X-load hoist
// all neutral-to-bad -> per-kernel polish exhausted. R16: STRUCTURAL — agg
// output row n feeds only GEMM row n, so fuse (agg 64 nodes -> LDS Yl[64][72]
// -> barrier -> 64-row MFMA tile) for layers 1->2 and 2->3: deletes bufG
// round-trip (2x 25.6MB) + 2 launch gaps. Bit-identical arithmetic.

#define ALIGN256(x) (((size_t)(x) + 255) & ~(size_t)255)

typedef _Float16 f16;
typedef f16 f16x8 __attribute__((ext_vector_type(8)));
typedef float f32x4 __attribute__((ext_vector_type(4)));

// ---------------- coarse histogram + fused scan (last block) ----------------

__global__ __launch_bounds__(256) void k_coarse(const int* __restrict__ ei,
                                                int* __restrict__ ccnt,
                                                int* __restrict__ done,
                                                int* __restrict__ cbase,
                                                int* __restrict__ cpos,
                                                int* __restrict__ row_start,
                                                int E, int N, int NBUK, int nblk) {
    __shared__ int h[512];
    __shared__ int lastblk;
    int t = threadIdx.x;
    for (int i = t; i < NBUK; i += 256) h[i] = 0;
    __syncthreads();
    int e0 = blockIdx.x * 8192;
    int e1 = min(e0 + 8192, E);
    for (int e = e0 + t; e < e1; e += 256) atomicAdd(&h[ei[E + e] >> 8], 1);
    __syncthreads();
    for (int i = t; i < NBUK; i += 256) {
        int c = h[i];
        if (c) atomicAdd(&ccnt[i], c);
    }
    __threadfence();
    if (t == 0) lastblk = (atomicAdd(done, 1) == nblk - 1) ? 1 : 0;
    __syncthreads();
    if (!lastblk) return;

    __shared__ int sd[256];
    int i0 = 2 * t, i1 = 2 * t + 1;
    int v0 = (i0 < NBUK) ? ccnt[i0] : 0;
    int v1 = (i1 < NBUK) ? ccnt[i1] : 0;
    int s = v0 + v1;
    sd[t] = s;
    __syncthreads();
    for (int off = 1; off < 256; off <<= 1) {
        int u = (t >= off) ? sd[t - off] : 0;
        __syncthreads();
        sd[t] += u;
        __syncthreads();
    }
    int base = sd[t] - s;
    if (i0 < NBUK) { cbase[i0] = base;      cpos[i0] = base; }
    if (i1 < NBUK) { cbase[i1] = base + v0; cpos[i1] = base + v0; }
    if (t == 0) { cbase[NBUK] = E; row_start[N] = E; }
}

// ---------------- pass A: coarse scatter; stage entry = (dst&255)<<24 | src -

__global__ __launch_bounds__(256) void k_passA(const int* __restrict__ ei,
                                               int* __restrict__ cpos,
                                               unsigned int* __restrict__ stage,
                                               int E, int NBUK) {
    __shared__ int h[512];
    __shared__ int base[512];
    int t = threadIdx.x;
    for (int i = t; i < NBUK; i += 256) h[i] = 0;
    __syncthreads();
    int e0 = blockIdx.x * 8192;
    int e1 = min(e0 + 8192, E);
    for (int e = e0 + t; e < e1; e += 256) atomicAdd(&h[ei[E + e] >> 8], 1);
    __syncthreads();
    for (int b = t; b < NBUK; b += 256) {
        int c = h[b];
        base[b] = c ? atomicAdd(&cpos[b], c) : 0;
        h[b] = 0;
    }
    __syncthreads();
    for (int e = e0 + t; e < e1; e += 256) {
        unsigned int s = (unsigned int)ei[e];
        int d = ei[E + e];
        int b = d >> 8;
        int off = base[b] + atomicAdd(&h[b], 1);
        stage[off] = ((unsigned int)(d & 255) << 24) | s;
    }
}

// ---------------- B1: per-bucket node counts (LDS atomics) -> row_start, dinv

__global__ __launch_bounds__(256) void k_B1(const unsigned int* __restrict__ stage,
                                            const int* __restrict__ cbase,
                                            int* __restrict__ row_start,
                                            float* __restrict__ dinv, int N) {
    __shared__ int cnt[256];
    __shared__ int sd[256];
    int b = blockIdx.x;
    int n0 = b << 8;
    int t = threadIdx.x;
    cnt[t] = 0;
    __syncthreads();
    int s0 = cbase[b], s1 = cbase[b + 1];
    for (int j = s0 + t; j < s1; j += 256) atomicAdd(&cnt[stage[j] >> 24], 1);
    __syncthreads();
    int c = cnt[t];
    sd[t] = c;
    __syncthreads();
    for (int off = 1; off < 256; off <<= 1) {
        int u = (t >= off) ? sd[t - off] : 0;
        __syncthreads();
        sd[t] += u;
        __syncthreads();
    }
    int excl = sd[t] - c;
    int node = n0 + t;
    if (node < N) {
        row_start[node] = s0 + excl;
        dinv[node] = 1.0f / sqrtf((float)(c + 1));   // +1 self-loop
    }
}

// ---------------- B2: fine scatter within bucket -> ep = (src, norm) --------

__global__ __launch_bounds__(256) void k_B2(const unsigned int* __restrict__ stage,
                                            const int* __restrict__ cbase,
                                            const int* __restrict__ row_start,
                                            const float* __restrict__ dinv,
                                            int2* __restrict__ ep, int N) {
    __shared__ int lpos[256];
    __shared__ float ld[256];
    int b = blockIdx.x;
    int n0 = b << 8;
    int t = threadIdx.x;
    int node = n0 + t;
    if (node < N) {
        lpos[t] = row_start[node];
        ld[t] = dinv[node];
    }
    __syncthreads();
    int s0 = cbase[b], s1 = cbase[b + 1];
    for (int j = s0 + t; j < s1; j += 256) {
        unsigned int v = stage[j];
        int li = v >> 24;
        int src = v & 0xFFFFFF;
        int slot = atomicAdd(&lpos[li], 1);
        ep[slot] = make_int2(src, __float_as_int(dinv[src] * ld[li]));
    }
}

// ---------------- agg inner body (shared by k_agg and fused kernel) ---------

__device__ __forceinline__ void fma8(float4& a0, float4& a1, uint4 hv, float w) {
    __half2* hp = (__half2*)&hv;
    float2 f0 = __half22float2(hp[0]);
    float2 f1 = __half22float2(hp[1]);
    float2 f2 = __half22float2(hp[2]);
    float2 f3 = __half22float2(hp[3]);
    a0.x += f0.x * w; a0.y += f0.y * w; a0.z += f1.x * w; a0.w += f1.y * w;
    a1.x += f2.x * w; a1.y += f2.y * w; a1.z += f3.x * w; a1.w += f3.y * w;
}

// Accumulate one node's neighbor sums over lq-chunk (8 feats); F=64 layout.
__device__ __forceinline__ void agg_edges(const __half* __restrict__ H,
                                          const int2* __restrict__ ep,
                                          int jb, int je, int lq,
                                          float4& a0, float4& a1) {
    int j = jb;
    for (; j + 8 <= je; j += 8) {
        int2 e0 = ep[j],     e1 = ep[j + 1], e2 = ep[j + 2], e3 = ep[j + 3];
        int2 e4 = ep[j + 4], e5 = ep[j + 5], e6 = ep[j + 6], e7 = ep[j + 7];
        uint4 h0 = *(const uint4*)&H[(size_t)e0.x * 64 + 8 * lq];
        uint4 h1 = *(const uint4*)&H[(size_t)e1.x * 64 + 8 * lq];
        uint4 h2 = *(const uint4*)&H[(size_t)e2.x * 64 + 8 * lq];
        uint4 h3 = *(const uint4*)&H[(size_t)e3.x * 64 + 8 * lq];
        uint4 h4 = *(const uint4*)&H[(size_t)e4.x * 64 + 8 * lq];
        uint4 h5 = *(const uint4*)&H[(size_t)e5.x * 64 + 8 * lq];
        uint4 h6 = *(const uint4*)&H[(size_t)e6.x * 64 + 8 * lq];
        uint4 h7 = *(const uint4*)&H[(size_t)e7.x * 64 + 8 * lq];
        fma8(a0, a1, h0, __int_as_float(e0.y));
        fma8(a0, a1, h1, __int_as_float(e1.y));
        fma8(a0, a1, h2, __int_as_float(e2.y));
        fma8(a0, a1, h3, __int_as_float(e3.y));
        fma8(a0, a1, h4, __int_as_float(e4.y));
        fma8(a0, a1, h5, __int_as_float(e5.y));
        fma8(a0, a1, h6, __int_as_float(e6.y));
        fma8(a0, a1, h7, __int_as_float(e7.y));
    }
    for (; j + 2 <= je; j += 2) {
        int2 e0 = ep[j], e1 = ep[j + 1];
        uint4 h0 = *(const uint4*)&H[(size_t)e0.x * 64 + 8 * lq];
        uint4 h1 = *(const uint4*)&H[(size_t)e1.x * 64 + 8 * lq];
        fma8(a0, a1, h0, __int_as_float(e0.y));
        fma8(a0, a1, h1, __int_as_float(e1.y));
    }
    if (j < je) {
        int2 e = ep[j];
        uint4 h = *(const uint4*)&H[(size_t)e.x * 64 + 8 * lq];
        fma8(a0, a1, h, __int_as_float(e.y));
    }
}

// ---------------- MFMA GEMM: Y[N,OUT](fp16) = X[N,K] @ W[K,OUT] -------------
// (gemm0 only now.) Block = 4 waves, 64 rows, NF col fragments. SWAPPED
// operands (W in A slot) -> row=lane&15, cols=4*(lane>>4)+reg -> 8B stores.
// k = 8h+j bijection shared by both operands. R15 X-hoist kept (neutral).

template <int K, int OUT, int NF, typename XT>
__global__ __launch_bounds__(256) void k_mgemm(const XT* __restrict__ X,
                                               const float* __restrict__ W,
                                               __half* __restrict__ Y, int N) {
    constexpr int NC = NF * 16;
    constexpr int NT = K / 32;
    __shared__ f16 Wl[NT * NF * 4 * 128];

    int tid = threadIdx.x;
    for (int idx = tid; idx < K * NC; idx += 256) {
        int k = idx / NC;
        int n = idx - k * NC;
        float v = (n < OUT) ? W[k * OUT + n] : 0.0f;
        int t = k >> 5, h = (k >> 3) & 3, j = k & 7, f = n >> 4, nn = n & 15;
        Wl[((t * NF + f) * 4 + h) * 128 + nn * 8 + j] = (f16)v;
    }
    __syncthreads();

    int lane = tid & 63;
    int wid = tid >> 6;
    int h = lane >> 4;
    int nn = lane & 15;
    int row = blockIdx.x * 64 + (wid << 4) + nn;
    bool valid = row < N;

    f16x8 xf[NT];
    if (valid) {
        if constexpr (sizeof(XT) == 4) {
            float4 u[NT][2];
            const float* xb = (const float*)X + (size_t)row * K + (h << 3);
#pragma unroll
            for (int t = 0; t < NT; ++t) {
                u[t][0] = *(const float4*)(xb + (t << 5));
                u[t][1] = *(const float4*)(xb + (t << 5) + 4);
            }
#pragma unroll
            for (int t = 0; t < NT; ++t) {
                xf[t][0] = (f16)u[t][0].x; xf[t][1] = (f16)u[t][0].y;
                xf[t][2] = (f16)u[t][0].z; xf[t][3] = (f16)u[t][0].w;
                xf[t][4] = (f16)u[t][1].x; xf[t][5] = (f16)u[t][1].y;
                xf[t][6] = (f16)u[t][1].z; xf[t][7] = (f16)u[t][1].w;
            }
        } else {
            const __half* xb = (const __half*)X + (size_t)row * K + (h << 3);
#pragma unroll
            for (int t = 0; t < NT; ++t)
                xf[t] = *(const f16x8*)(xb + (t << 5));
        }
    } else {
#pragma unroll
        for (int t = 0; t < NT; ++t)
#pragma unroll
            for (int j = 0; j < 8; ++j) xf[t][j] = (f16)0.f;
    }

    f32x4 acc[NF];
#pragma unroll
    for (int f = 0; f < NF; ++f) acc[f] = (f32x4){0.f, 0.f, 0.f, 0.f};

#pragma unroll
    for (int t = 0; t < NT; ++t) {
#pragma unroll
        for (int f = 0; f < NF; ++f) {
            f16x8 wf = *(const f16x8*)&Wl[((t * NF + f) * 4 + h) * 128 + nn * 8];
            acc[f] = __builtin_amdgcn_mfma_f32_16x16x32_f16(wf, xf[t], acc[f], 0, 0, 0);
        }
    }

    if (valid) {
#pragma unroll
        for (int f = 0; f < NF; ++f) {
            int c = (f << 4) + (h << 2);
            if (c < OUT) {
                __half2 p0 = __floats2half2_rn(acc[f][0], acc[f][1]);
                __half2 p1 = __floats2half2_rn(acc[f][2], acc[f][3]);
                uint2 pk = make_uint2(*(unsigned int*)&p0, *(unsigned int*)&p1);
                *(uint2*)&Y[(size_t)row * OUT + c] = pk;
            }
        }
    }
}

// ---------------- fused agg(64 nodes)+bias+relu -> LDS -> MFMA GEMM ---------
// Agg phase: 2 passes x 32 nodes (unroll-8 body unchanged), result packed
// fp16 into Yl[64][72] (stride-72 pad: rows 144B apart -> 2-way LDS aliasing
// only, free per m136). Barrier. GEMM phase: identical 64-row MFMA tile
// reading Yl instead of global. Bit-identical arithmetic vs unfused path.

template <int OUT, int NF>
__global__ __launch_bounds__(256) void k_agg_gemm(const __half* __restrict__ H,
                                                  const int* __restrict__ row_start,
                                                  const int2* __restrict__ ep,
                                                  const float* __restrict__ dinv,
                                                  const float* __restrict__ bias,
                                                  const float* __restrict__ W,
                                                  __half* __restrict__ Y, int N) {
    constexpr int NC = NF * 16;
    constexpr int NT = 2;                    // K = 64
    __shared__ f16 Wl[NT * NF * 4 * 128];    // <=16KB
    __shared__ f16 Yl[64 * 72];              // 9KB, padded stride 72

    int tid = threadIdx.x;
    // stage W (swizzled fragment order) — consumed after the barrier
    for (int idx = tid; idx < 64 * NC; idx += 256) {
        int k = idx / NC;
        int n = idx - k * NC;
        float v = (n < OUT) ? W[k * OUT + n] : 0.0f;
        int t = k >> 5, hh = (k >> 3) & 3, j = k & 7, f = n >> 4, nn = n & 15;
        Wl[((t * NF + f) * 4 + hh) * 128 + nn * 8 + j] = (f16)v;
    }

    int lane = tid & 63;
    int sub = lane >> 3;        // node within wave (0..7)
    int lq = lane & 7;          // 8-feature chunk
    int wid = tid >> 6;

    // ---- agg phase: 2 passes x 32 nodes -> Yl ----
#pragma unroll
    for (int pass = 0; pass < 2; ++pass) {
        int lrow = pass * 32 + wid * 8 + sub;
        int node = blockIdx.x * 64 + lrow;
        uint4 pk = make_uint4(0, 0, 0, 0);
        if (node < N) {
            int jb = row_start[node];
            int je = row_start[node + 1];
            float dv = dinv[node];
            float4 a0 = make_float4(0.f, 0.f, 0.f, 0.f);
            float4 a1 = make_float4(0.f, 0.f, 0.f, 0.f);
            uint4 hv = *(const uint4*)&H[(size_t)node * 64 + 8 * lq];
            fma8(a0, a1, hv, dv * dv);
            agg_edges(H, ep, jb, je, lq, a0, a1);
            float4 b0 = *(const float4*)&bias[8 * lq];
            float4 b1 = *(const float4*)&bias[8 * lq + 4];
            a0.x += b0.x; a0.y += b0.y; a0.z += b0.z; a0.w += b0.w;
            a1.x += b1.x; a1.y += b1.y; a1.z += b1.z; a1.w += b1.w;
            a0.x = fmaxf(a0.x, 0.f); a0.y = fmaxf(a0.y, 0.f);
            a0.z = fmaxf(a0.z, 0.f); a0.w = fmaxf(a0.w, 0.f);
            a1.x = fmaxf(a1.x, 0.f); a1.y = fmaxf(a1.y, 0.f);
            a1.z = fmaxf(a1.z, 0.f); a1.w = fmaxf(a1.w, 0.f);
            __half2 p0 = __floats2half2_rn(a0.x, a0.y);
            __half2 p1 = __floats2half2_rn(a0.z, a0.w);
            __half2 p2 = __floats2half2_rn(a1.x, a1.y);
            __half2 p3 = __floats2half2_rn(a1.z, a1.w);
            pk = make_uint4(*(unsigned int*)&p0, *(unsigned int*)&p1,
                            *(unsigned int*)&p2, *(unsigned int*)&p3);
        }
        *(uint4*)&Yl[lrow * 72 + 8 * lq] = pk;
    }
    __syncthreads();

    // ---- gemm phase: 64-row MFMA tile off Yl ----
    int h = lane >> 4;
    int nn = lane & 15;
    int lrow = (wid << 4) + nn;
    int row = blockIdx.x * 64 + lrow;

    f32x4 acc[NF];
#pragma unroll
    for (int f = 0; f < NF; ++f) acc[f] = (f32x4){0.f, 0.f, 0.f, 0.f};

#pragma unroll
    for (int t = 0; t < NT; ++t) {
        f16x8 xf = *(const f16x8*)&Yl[lrow * 72 + (t << 5) + (h << 3)];
#pragma unroll
        for (int f = 0; f < NF; ++f) {
            f16x8 wf = *(const f16x8*)&Wl[((t * NF + f) * 4 + h) * 128 + nn * 8];
            acc[f] = __builtin_amdgcn_mfma_f32_16x16x32_f16(wf, xf, acc[f], 0, 0, 0);
        }
    }

    if (row < N) {
#pragma unroll
        for (int f = 0; f < NF; ++f) {
            int c = (f << 4) + (h << 2);
            if (c < OUT) {
                __half2 p0 = __floats2half2_rn(acc[f][0], acc[f][1]);
                __half2 p1 = __floats2half2_rn(acc[f][2], acc[f][3]);
                uint2 pk = make_uint2(*(unsigned int*)&p0, *(unsigned int*)&p1);
                *(uint2*)&Y[(size_t)row * OUT + c] = pk;
            }
        }
    }
}

// ---------------- final aggregation (F=40, writes float out) ----------------

template <int NV, int F, int RELU, typename OutT>
__global__ __launch_bounds__(256) void k_agg(const __half* __restrict__ H,
                                             const int* __restrict__ row_start,
                                             const int2* __restrict__ ep,
                                             const float* __restrict__ dinv,
                                             const float* __restrict__ bias,
                                             OutT* __restrict__ out, int N) {
    int tid = threadIdx.x;
    int lane = tid & 63;
    int sub = lane >> 3;
    int lq = lane & 7;
    int node = blockIdx.x * 32 + (tid >> 6) * 8 + sub;
    if (node >= N) return;
    const bool act = (NV == 8) || (lq < NV);

    int jb = row_start[node];
    int je = row_start[node + 1];
    float dv = dinv[node];

    float4 a0 = make_float4(0.f, 0.f, 0.f, 0.f);
    float4 a1 = make_float4(0.f, 0.f, 0.f, 0.f);
    if (act) {
        uint4 hv = *(const uint4*)&H[(size_t)node * F + 8 * lq];
        fma8(a0, a1, hv, dv * dv);
    }

    int j = jb;
    for (; j + 8 <= je; j += 8) {
        int2 e0 = ep[j],     e1 = ep[j + 1], e2 = ep[j + 2], e3 = ep[j + 3];
        int2 e4 = ep[j + 4], e5 = ep[j + 5], e6 = ep[j + 6], e7 = ep[j + 7];
        if (act) {
            uint4 h0 = *(const uint4*)&H[(size_t)e0.x * F + 8 * lq];
            uint4 h1 = *(const uint4*)&H[(size_t)e1.x * F + 8 * lq];
            uint4 h2 = *(const uint4*)&H[(size_t)e2.x * F + 8 * lq];
            uint4 h3 = *(const uint4*)&H[(size_t)e3.x * F + 8 * lq];
            uint4 h4 = *(const uint4*)&H[(size_t)e4.x * F + 8 * lq];
            uint4 h5 = *(const uint4*)&H[(size_t)e5.x * F + 8 * lq];
            uint4 h6 = *(const uint4*)&H[(size_t)e6.x * F + 8 * lq];
            uint4 h7 = *(const uint4*)&H[(size_t)e7.x * F + 8 * lq];
            fma8(a0, a1, h0, __int_as_float(e0.y));
            fma8(a0, a1, h1, __int_as_float(e1.y));
            fma8(a0, a1, h2, __int_as_float(e2.y));
            fma8(a0, a1, h3, __int_as_float(e3.y));
            fma8(a0, a1, h4, __int_as_float(e4.y));
            fma8(a0, a1, h5, __int_as_float(e5.y));
            fma8(a0, a1, h6, __int_as_float(e6.y));
            fma8(a0, a1, h7, __int_as_float(e7.y));
        }
    }
    for (; j + 2 <= je; j += 2) {
        int2 e0 = ep[j], e1 = ep[j + 1];
        if (act) {
            uint4 h0 = *(const uint4*)&H[(size_t)e0.x * F + 8 * lq];
            uint4 h1 = *(const uint4*)&H[(size_t)e1.x * F + 8 * lq];
            fma8(a0, a1, h0, __int_as_float(e0.y));
            fma8(a0, a1, h1, __int_as_float(e1.y));
        }
    }
    if (j < je) {
        int2 e = ep[j];
        if (act) {
            uint4 h = *(const uint4*)&H[(size_t)e.x * F + 8 * lq];
            fma8(a0, a1, h, __int_as_float(e.y));
        }
    }

    if (act) {
        float4 b0 = *(const float4*)&bias[8 * lq];
        float4 b1 = *(const float4*)&bias[8 * lq + 4];
        a0.x += b0.x; a0.y += b0.y; a0.z += b0.z; a0.w += b0.w;
        a1.x += b1.x; a1.y += b1.y; a1.z += b1.z; a1.w += b1.w;
        if (RELU) {
            a0.x = fmaxf(a0.x, 0.f); a0.y = fmaxf(a0.y, 0.f);
            a0.z = fmaxf(a0.z, 0.f); a0.w = fmaxf(a0.w, 0.f);
            a1.x = fmaxf(a1.x, 0.f); a1.y = fmaxf(a1.y, 0.f);
            a1.z = fmaxf(a1.z, 0.f); a1.w = fmaxf(a1.w, 0.f);
        }
        if constexpr (sizeof(OutT) == 2) {
            __half2 p0 = __floats2half2_rn(a0.x, a0.y);
            __half2 p1 = __floats2half2_rn(a0.z, a0.w);
            __half2 p2 = __floats2half2_rn(a1.x, a1.y);
            __half2 p3 = __floats2half2_rn(a1.z, a1.w);
            uint4 pk = make_uint4(*(unsigned int*)&p0, *(unsigned int*)&p1,
                                  *(unsigned int*)&p2, *(unsigned int*)&p3);
            *(uint4*)&out[(size_t)node * F + 8 * lq] = pk;
        } else {
            *(float4*)&out[(size_t)node * F + 8 * lq] = a0;
            *(float4*)&out[(size_t)node * F + 8 * lq + 4] = a1;
        }
    }
}

// ---------------- launch ----------------

extern "C" void kernel_launch(void* const* d_in, const int* in_sizes, int n_in,
                              void* d_out, int out_size, void* d_ws, size_t ws_size,
                              hipStream_t stream) {
    const float* x  = (const float*)d_in[0];
    const int*   ei = (const int*)d_in[1];
    const float* W0 = (const float*)d_in[2];
    const float* b0 = (const float*)d_in[3];
    const float* W1 = (const float*)d_in[4];
    const float* b1 = (const float*)d_in[5];
    const float* W2 = (const float*)d_in[6];
    const float* b2 = (const float*)d_in[7];
    float* out = (float*)d_out;

    const int N = in_sizes[0] / 128;
    const int E = in_sizes[1] / 2;
    const int NBUK = (N + 255) >> 8;   // coarse buckets of 256 nodes (<=512)

    char* w = (char*)d_ws;
    size_t off = 0;
    // zeroed stretch: ccnt[NBUK], done
    int*    ccnt      = (int*)(w + off);    off = ALIGN256(off + (size_t)(NBUK + 1) * 4);
    int*    done      = ccnt + NBUK;
    int*    cbase     = (int*)(w + off);    off = ALIGN256(off + (size_t)(NBUK + 1) * 4);
    int*    cpos      = (int*)(w + off);    off = ALIGN256(off + (size_t)NBUK * 4);
    int*    row_start = (int*)(w + off);    off = ALIGN256(off + (size_t)(N + 1) * 4);
    float*  dinv      = (float*)(w + off);  off = ALIGN256(off + (size_t)N * 4);
    int2*   ep        = (int2*)(w + off);   off = ALIGN256(off + (size_t)E * 8);
    __half* bufH      = (__half*)(w + off); off = ALIGN256(off + (size_t)N * 64 * 2);
    __half* bufG      = (__half*)(w + off); off = ALIGN256(off + (size_t)N * 64 * 2);
    unsigned int* stage = (unsigned int*)bufG;   // dead before fused1 writes bufG

    const int gGemm  = (N + 63) / 64;
    const int gAgg   = (N + 31) / 32;
    const int gFused = (N + 63) / 64;
    const int gPA    = (E + 8191) / 8192;

    hipMemsetAsync(ccnt, 0, (size_t)(NBUK + 1) * 4, stream);
    k_mgemm<128, 64, 4><<<gGemm, 256, 0, stream>>>(x, W0, bufH, N);
    k_coarse<<<gPA, 256, 0, stream>>>(ei, ccnt, done, cbase, cpos, row_start, E, N, NBUK, gPA);
    k_passA<<<gPA, 256, 0, stream>>>(ei, cpos, stage, E, NBUK);
    k_B1<<<NBUK, 256, 0, stream>>>(stage, cbase, row_start, dinv, N);
    k_B2<<<NBUK, 256, 0, stream>>>(stage, cbase, row_start, dinv, ep, N);

    // layer 1: agg(+b0,relu) fused with gemm(W1) -> bufG
    k_agg_gemm<64, 4><<<gFused, 256, 0, stream>>>(bufH, row_start, ep, dinv, b0, W1, bufG, N);
    // layer 2: agg(+b1,relu) fused with gemm(W2, OUT=40) -> bufH
    k_agg_gemm<40, 3><<<gFused, 256, 0, stream>>>(bufG, row_start, ep, dinv, b1, W2, bufH, N);
    // layer 3: final agg(+b2, no relu) -> float out
    k_agg<5, 40, 0, float><<<gAgg, 256, 0, stream>>>(bufH, row_start, ep, dinv, b2, out, N);
}